// Round 12
// baseline (275.585 us; speedup 1.0000x reference)
//
#include <hip/hip_runtime.h>
#include <hip/hip_bf16.h>
#include <stdint.h>

#define B_ 256
#define D_ 10
#define P_ 1152
#define I_ 16
#define J_ 8

#define NPG 16      // p-groups (s_part slices)
#define PRR 72      // p per block (= P_/NPG)
#define NB 8        // b per block

// Fused routing round: recompute u = W.x on the fly — u_hat is NEVER
// materialized (r3-r11: six producer structures all pinned at ~2 TB/s write,
// ~47 us for the 94 MB store; reads of the same buffer run 4.7 TB/s).
// Team of 8 lanes owns (b,p); u[10][2], t[10][2], sacc[10][2] in registers.
// W read per-d direct from global: per-step block working set ~45 KB (L1/L2
// hot); each wave's W read = one contiguous 512B broadcast (8 teams share p).
// Grid: bid = bc*16 + pg -> pg % 8 == XCD: per-XCD W slices (2x368KB) +
// x columns (~1.2MB) stay L2-resident.
// RND=0: c uniform (skip beta/softmax). RND=1: t=g0*s0. RND=2: t=g0*s0+g1*s1.
template<int RND>
__global__ __launch_bounds__(512, 2) void k_round(
    const float* __restrict__ x, const float* __restrict__ W,
    const float* __restrict__ s0, const float* __restrict__ s1,
    const float* __restrict__ n2v, float* __restrict__ s_part)
{
    const int bid = blockIdx.x;
    const int pg = bid & 15;         // p-group; XCD = pg % 8
    const int bc = bid >> 4;         // 0..31
    const int tid = threadIdx.x;
    const int c = tid & 7;           // i-pair: i = 2c, 2c+1
    const int tm = tid >> 3;         // team 0..63
    const int b_l = tm & 7;
    const int pidx = tm >> 3;        // 0..7 concurrent p
    const int b = bc * NB + b_l;

    __shared__ float lsum[8][NB][D_ * I_];   // 40 KB

    // t (routing direction) in registers: t[d][2] for this lane's (b, c)
    float t0[D_], t1[D_];
    if (RND > 0) {
        const float n20 = n2v[0];
        const float g0 = (n20 / (n20 + 1.f)) / (sqrtf(n20) + 1e-7f);
        const float* sb0 = s0 + (size_t)b * (D_ * I_) + 2 * c;
        #pragma unroll
        for (int d = 0; d < D_; ++d) {
            t0[d] = g0 * sb0[d * 16];
            t1[d] = g0 * sb0[d * 16 + 1];
        }
        if (RND == 2) {
            const float n21 = n2v[1];
            const float g1 = (n21 / (n21 + 1.f)) / (sqrtf(n21) + 1e-7f);
            const float* sb1 = s1 + (size_t)b * (D_ * I_) + 2 * c;
            #pragma unroll
            for (int d = 0; d < D_; ++d) {
                t0[d] += g1 * sb1[d * 16];
                t1[d] += g1 * sb1[d * 16 + 1];
            }
        }
    }

    float sa0[D_], sa1[D_];
    #pragma unroll
    for (int d = 0; d < D_; ++d) { sa0[d] = 0.f; sa1[d] = 0.f; }

    for (int st = 0; st < PRR / 8; ++st) {
        const int p = pg * PRR + st * 8 + pidx;
        const float4* xp = (const float4*)(x + ((size_t)b * P_ + p) * J_);
        const float4 xA = xp[0], xB = xp[1];
        const float4* wp = (const float4*)(W + ((size_t)p * I_ + 2 * c) * J_);

        float u0[D_], u1[D_], beta[D_];
        #pragma unroll
        for (int d = 0; d < D_; ++d) {
            const float4 wA = wp[0], wB = wp[1], wC = wp[2], wD = wp[3];
            wp += (size_t)P_ * 32;    // next d: stride P_*16*8 floats
            u0[d] = wA.x*xA.x + wA.y*xA.y + wA.z*xA.z + wA.w*xA.w
                  + wB.x*xB.x + wB.y*xB.y + wB.z*xB.z + wB.w*xB.w;
            u1[d] = wC.x*xA.x + wC.y*xA.y + wC.z*xA.z + wC.w*xA.w
                  + wD.x*xB.x + wD.y*xB.y + wD.z*xB.z + wD.w*xB.w;
            if (RND > 0) beta[d] = u0[d] * t0[d] + u1[d] * t1[d];
        }

        if (RND > 0) {
            // team-reduce beta over the 8 i-pair lanes (full i-dot)
            #pragma unroll
            for (int d = 0; d < D_; ++d) {
                beta[d] += __shfl_xor(beta[d], 1);
                beta[d] += __shfl_xor(beta[d], 2);
                beta[d] += __shfl_xor(beta[d], 4);
            }
            float m = beta[0];
            #pragma unroll
            for (int d = 1; d < D_; ++d) m = fmaxf(m, beta[d]);
            float Z = 0.f;
            #pragma unroll
            for (int d = 0; d < D_; ++d) { beta[d] = __expf(beta[d] - m); Z += beta[d]; }
            const float rz = 1.f / Z;
            #pragma unroll
            for (int d = 0; d < D_; ++d) {
                const float cd = beta[d] * rz;
                sa0[d] += cd * u0[d];
                sa1[d] += cd * u1[d];
            }
        } else {
            #pragma unroll
            for (int d = 0; d < D_; ++d) { sa0[d] += u0[d]; sa1[d] += u1[d]; }
        }
    }

    // block reduce over the 8 concurrent-p teams sharing each b
    #pragma unroll
    for (int d = 0; d < D_; ++d) {
        lsum[pidx][b_l][d * 16 + 2 * c]     = sa0[d];
        lsum[pidx][b_l][d * 16 + 2 * c + 1] = sa1[d];
    }
    __syncthreads();
    for (int k = tid; k < NB * D_ * I_; k += 512) {
        const int bb = k / (D_ * I_);
        const int di = k - bb * (D_ * I_);
        float v = 0.f;
        #pragma unroll
        for (int q = 0; q < 8; ++q) v += lsum[q][bb][di];
        s_part[(size_t)pg * (B_ * D_ * I_) + (size_t)(bc * NB + bb) * (D_ * I_) + di] = v;
    }
}

// Sum the 16 p-group partials -> sout (x scale), n2[.] += sum sout^2.
__global__ __launch_bounds__(256) void k_sred(const float* __restrict__ s_part,
                                              float* __restrict__ sout,
                                              float* __restrict__ n2, float scale)
{
    const int gid = blockIdx.x * 256 + threadIdx.x;   // (b,d,i)
    float v = 0.f;
    #pragma unroll
    for (int pt = 0; pt < NPG; ++pt) v += s_part[(size_t)pt * (B_ * D_ * I_) + gid];
    v *= scale;
    sout[gid] = v;
    float v2 = v * v;
    #pragma unroll
    for (int st = 1; st < 64; st <<= 1) v2 += __shfl_xor(v2, st);
    __shared__ float r4[4];
    const int lane = threadIdx.x & 63, wave = threadIdx.x >> 6;
    if (lane == 0) r4[wave] = v2;
    __syncthreads();
    if (threadIdx.x == 0) atomicAdd(n2, r4[0] + r4[1] + r4[2] + r4[3]);
}

// Final in-place rescale: out *= g(n2_2)
__global__ void k_out(float* __restrict__ out, const float* __restrict__ n2p)
{
    const int i = blockIdx.x * 256 + threadIdx.x;
    const float n2 = *n2p;
    const float g = (n2 / (n2 + 1.f)) / (sqrtf(n2) + 1e-7f);
    out[i] *= g;
}

extern "C" void kernel_launch(void* const* d_in, const int* in_sizes, int n_in,
                              void* d_out, int out_size, void* d_ws, size_t ws_size,
                              hipStream_t stream)
{
    const float* x = (const float*)d_in[0];   // [256,1152,8]
    const float* W = (const float*)d_in[1];   // [10,1152,16,8]
    float* out = (float*)d_out;               // [256,10,16]

    float* ws = (float*)d_ws;
    float* s_part = ws;                                  // [16][B*D*I] = 2.62 MB
    float* s0 = s_part + (size_t)NPG * B_ * D_ * I_;     // [B*D*I]
    float* s1 = s0 + B_ * D_ * I_;                       // [B*D*I]
    float* n2 = s1 + B_ * D_ * I_;                       // [3]

    (void)hipMemsetAsync(n2, 0, 3 * sizeof(float), stream);

    const int grid = 32 * NPG;   // 512 blocks

    // r = 0: uniform c = 0.1 (applied as scale in k_sred)
    k_round<0><<<grid, 512, 0, stream>>>(x, W, s0, s1, n2, s_part);
    k_sred<<<(B_ * D_ * I_) / 256, 256, 0, stream>>>(s_part, s0, n2 + 0, 0.1f);
    // r = 1: t = g0*s0
    k_round<1><<<grid, 512, 0, stream>>>(x, W, s0, s1, n2, s_part);
    k_sred<<<(B_ * D_ * I_) / 256, 256, 0, stream>>>(s_part, s1, n2 + 1, 1.0f);
    // r = 2: t = g0*s0 + g1*s1; raw s2 -> d_out
    k_round<2><<<grid, 512, 0, stream>>>(x, W, s0, s1, n2, s_part);
    k_sred<<<(B_ * D_ * I_) / 256, 256, 0, stream>>>(s_part, out, n2 + 2, 1.0f);
    // out = g2 * s2 (in place)
    k_out<<<(B_ * D_ * I_) / 256, 256, 0, stream>>>(out, n2 + 2);
}